// Round 9
// baseline (842.638 us; speedup 1.0000x reference)
//
#include <hip/hip_runtime.h>
#include <hip/hip_bf16.h>

#define HIDDEN   2880
#define INTER    2880
#define NEXP     8
#define GUP_ROWS 5760
#define NPAIR    2048

#define NKT   90             // k-tiles of 32
#define BM    320            // one m-tile per expert (n_e ~ 256+/-15)
#define BN1   128
#define BN2   96

#define TILE_B  20480        // global image per (tile,kt): 4 planes x 320 rows x 16B
#define PLANE_G 5120
#define PLANE_L 5184         // LDS plane stride (+64B pad: 2-way residual = free)
#define ABUF_L  20736        // 4*PLANE_L

#define MAXTILES 12
#define IMG_BYTES ((size_t)MAXTILES * NKT * TILE_B)   // 22.1 MB

using bf16x8 = __attribute__((ext_vector_type(8))) short;
using f32x4  = __attribute__((ext_vector_type(4))) float;

typedef const __attribute__((address_space(1))) unsigned GBuf;
typedef __attribute__((address_space(3))) unsigned LBuf;

__device__ __forceinline__ void gl2lds(const void* g, void* l) {
  __builtin_amdgcn_global_load_lds((GBuf*)g, (LBuf*)l, 16, 0, 0);
}

__device__ __forceinline__ unsigned cvt2bf(float a, float b) {
  union { __hip_bfloat16 h; unsigned short s; } x, y;
  x.h = __float2bfloat16(a);
  y.h = __float2bfloat16(b);
  return (unsigned)x.s | ((unsigned)y.s << 16);
}

// ---------------- routing ----------------
// meta: [0..7]=counts [8..15]=row offsets [16..23]=cursor [24..31]=tile base
__global__ void route_count(const int* __restrict__ eidx, int* __restrict__ meta) {
  __shared__ int cnt[NEXP];
  int t = threadIdx.x;
  if (t < NEXP) cnt[t] = 0;
  __syncthreads();
  for (int a = t; a < NPAIR; a += 256) atomicAdd(&cnt[eidx[a]], 1);
  __syncthreads();
  if (t == 0) {
    int off = 0, toff = 0;
    for (int e = 0; e < NEXP; ++e) {
      meta[e] = cnt[e];
      meta[8 + e] = off;
      meta[16 + e] = off;
      meta[24 + e] = toff;
      off += cnt[e];
      toff += (cnt[e] + BM - 1) / BM;
    }
  }
}

__global__ void route_scatter(const int* __restrict__ eidx, int* __restrict__ meta,
                              int* __restrict__ list) {
  int a = blockIdx.x * 256 + threadIdx.x;
  int e = eidx[a];
  int pos = atomicAdd(&meta[16 + e], 1);
  list[pos] = a;
}

// ---------------- gather A rows -> bf16 tiled fragment image ----------------
// layout: [tile][kt][kq 0..3][row 0..319][16B]
__global__ void gather_a(const float* __restrict__ t, const int* __restrict__ eidx,
                         const int* __restrict__ meta, const int* __restrict__ list,
                         char* __restrict__ atile) {
  const int i = blockIdx.x;
  const int a = list[i];
  const int e = eidx[a];
  const int r = i - meta[8 + e];
  const int tile = meta[24 + e] + r / BM;
  const int row = r % BM;
  const float* src = t + (size_t)(a >> 2) * HIDDEN;
  for (int ch = threadIdx.x; ch < HIDDEN / 8; ch += 256) {
    int kt = ch >> 2, kq = ch & 3;
    const float4* s = (const float4*)(src + ch * 8);
    float4 v0 = s[0], v1 = s[1];
    uint4 w;
    w.x = cvt2bf(v0.x, v0.y); w.y = cvt2bf(v0.z, v0.w);
    w.z = cvt2bf(v1.x, v1.y); w.w = cvt2bf(v1.z, v1.w);
    *(uint4*)(atile + (size_t)(tile * NKT + kt) * TILE_B + kq * PLANE_G + row * 16) = w;
  }
}

// ---------------- GEMM1: 10 waves (5 wm x 2 wn), tile 320x128, wave 64x64 ----------------
// LDS: A 2x20736 (gl2lds, padded planes) + B 2x8192 (bf16, reg-staged) = 57856.
__global__ __launch_bounds__(640, 5)
void gemm1_swiglu(const char* __restrict__ aimg,
                  const float* __restrict__ gup,
                  const float* __restrict__ gub,
                  const int* __restrict__ meta,
                  char* __restrict__ uimg)
{
  const int e = blockIdx.x, nt = blockIdx.y, mt = blockIdx.z;
  const int n_e = meta[e];
  const int m0 = mt * BM;
  if (m0 >= n_e) return;
  const int tile = meta[24 + e] + mt;

  __shared__ __align__(16) char lds[2 * ABUF_L + 2 * 8192];
  char* ldsB = lds + 2 * ABUF_L;

  const int tid = threadIdx.x, lane = tid & 63, wid = tid >> 6;
  const int wm = wid >> 1, wn = wid & 1;
  const int kq = lane >> 4, l15 = lane & 15;

  const char* aSrcBase = aimg + (size_t)tile * NKT * TILE_B;
  // A staging: 20 chunks of 1KB, 2 per wave
  const char* srcA[2]; int dstA[2];
  #pragma unroll
  for (int j = 0; j < 2; ++j) {
    int c = wid * 2 + j;
    srcA[j] = aSrcBase + c * 1024 + lane * 16;
    dstA[j] = (c / 5) * PLANE_L + (c % 5) * 1024;
  }
  // B staging: threads 0..511, col = tid>>2 (0..127), seg = tid&3
  const bool hasB = (tid < 512);
  const int bcol = tid >> 2, bseg = tid & 3;
  const float* bSrc = gup + ((size_t)(e * GUP_ROWS + nt * BN1 + bcol)) * HIDDEN + bseg * 8;
  const int bDst = bcol * 64 + bseg * 16;

  f32x4 acc[4][4];
  #pragma unroll
  for (int fm = 0; fm < 4; ++fm)
    #pragma unroll
    for (int fn = 0; fn < 4; ++fn)
      acc[fm][fn] = f32x4{0.f, 0.f, 0.f, 0.f};

  float4 rb0, rb1;
  auto STAGEA = [&](int kt, int buf) {
    #pragma unroll
    for (int j = 0; j < 2; ++j)
      gl2lds(srcA[j] + (size_t)kt * TILE_B, lds + buf * ABUF_L + dstA[j]);
  };
  auto LOADB = [&](int kt) {
    if (hasB) {
      rb0 = *(const float4*)(bSrc + (size_t)kt * 32);
      rb1 = *(const float4*)(bSrc + (size_t)kt * 32 + 4);
    }
  };
  auto WRITEB = [&](int buf) {
    if (hasB) {
      uint4 w;
      w.x = cvt2bf(rb0.x, rb0.y); w.y = cvt2bf(rb0.z, rb0.w);
      w.z = cvt2bf(rb1.x, rb1.y); w.w = cvt2bf(rb1.z, rb1.w);
      *(uint4*)(ldsB + buf * 8192 + bDst) = w;
    }
  };

  auto COMP = [&](int buf) {
    const char* aB = lds + buf * ABUF_L + kq * PLANE_L + (wm * 64 + l15) * 16;
    const char* bB = ldsB + buf * 8192 + (wn * 64 + l15) * 64 + kq * 16;
    bf16x8 af[4], bf[4];
    #pragma unroll
    for (int fm = 0; fm < 4; ++fm) af[fm] = *(const bf16x8*)(aB + fm * 256);
    #pragma unroll
    for (int fn = 0; fn < 4; ++fn) bf[fn] = *(const bf16x8*)(bB + fn * 1024);
    #pragma unroll
    for (int fm = 0; fm < 4; ++fm)
      #pragma unroll
      for (int fn = 0; fn < 4; ++fn)
        acc[fm][fn] = __builtin_amdgcn_mfma_f32_16x16x32_bf16(af[fm], bf[fn], acc[fm][fn], 0, 0, 0);
  };

  STAGEA(0, 0);
  LOADB(0);
  WRITEB(0);
  __syncthreads();
  for (int kt = 0; kt < NKT; ++kt) {
    int nb = (kt + 1) & 1;
    if (kt + 1 < NKT) { STAGEA(kt + 1, nb); LOADB(kt + 1); }
    COMP(kt & 1);
    if (kt + 1 < NKT) WRITEB(nb);
    __syncthreads();
  }

  // epilogue: +bias, swiglu (even col = glu, odd = lin), write u into uimg
  #pragma unroll
  for (int fm = 0; fm < 4; ++fm) {
    #pragma unroll
    for (int fn = 0; fn < 4; ++fn) {
      const int colg = nt * BN1 + wn * 64 + fn * 16 + l15;
      const float bias = gub[e * GUP_ROWS + colg];
      #pragma unroll
      for (int j = 0; j < 4; ++j) {
        float h = acc[fm][fn][j] + bias;
        float other = __shfl_xor(h, 1, 64);
        int rowin = wm * 64 + fm * 16 + kq * 4 + j;
        if (!(lane & 1) && (m0 + rowin) < n_e) {
          float xg = fminf(h, 7.0f);
          float xl = fminf(fmaxf(other, -7.0f), 7.0f);
          float og = xg / (1.0f + __expf(-1.702f * xg));
          float uv = og * (xl + 1.0f);
          int uc = colg >> 1;
          int kt2 = uc >> 5, kq2 = (uc >> 3) & 3;
          *(__hip_bfloat16*)(uimg + (size_t)(tile * NKT + kt2) * TILE_B +
              kq2 * PLANE_G + rowin * 16 + (uc & 7) * 2) = __float2bfloat16(uv);
        }
      }
    }
  }
}

// ---------------- GEMM2: 10 waves (5 wm x 2 wn), tile 320x96, wave 64x48 ----------------
// LDS: A 2x20736 + B 2x6144 = 53760.
__global__ __launch_bounds__(640, 5)
void gemm2_down(const char* __restrict__ uimg,
                const float* __restrict__ dwn,
                const float* __restrict__ dbias,
                const int* __restrict__ meta,
                const int* __restrict__ list,
                float* __restrict__ out)
{
  const int e = blockIdx.x, nt = blockIdx.y, mt = blockIdx.z;
  const int n_e = meta[e];
  const int m0 = mt * BM;
  if (m0 >= n_e) return;
  const int base = meta[8 + e];
  const int tile = meta[24 + e] + mt;

  __shared__ __align__(16) char lds[2 * ABUF_L + 2 * 6144];
  char* ldsB = lds + 2 * ABUF_L;

  const int tid = threadIdx.x, lane = tid & 63, wid = tid >> 6;
  const int wm = wid >> 1, wn = wid & 1;
  const int kq = lane >> 4, l15 = lane & 15;

  const char* aSrcBase = uimg + (size_t)tile * NKT * TILE_B;
  const char* srcA[2]; int dstA[2];
  #pragma unroll
  for (int j = 0; j < 2; ++j) {
    int c = wid * 2 + j;
    srcA[j] = aSrcBase + c * 1024 + lane * 16;
    dstA[j] = (c / 5) * PLANE_L + (c % 5) * 1024;
  }
  const bool hasB = (tid < 384);
  const int bcol = tid >> 2, bseg = tid & 3;
  const float* bSrc = dwn + ((size_t)(e * HIDDEN + nt * BN2 + bcol)) * INTER + bseg * 8;
  const int bDst = bcol * 64 + bseg * 16;

  f32x4 acc[4][3];
  #pragma unroll
  for (int fm = 0; fm < 4; ++fm)
    #pragma unroll
    for (int fn = 0; fn < 3; ++fn)
      acc[fm][fn] = f32x4{0.f, 0.f, 0.f, 0.f};

  float4 rb0, rb1;
  auto STAGEA = [&](int kt, int buf) {
    #pragma unroll
    for (int j = 0; j < 2; ++j)
      gl2lds(srcA[j] + (size_t)kt * TILE_B, lds + buf * ABUF_L + dstA[j]);
  };
  auto LOADB = [&](int kt) {
    if (hasB) {
      rb0 = *(const float4*)(bSrc + (size_t)kt * 32);
      rb1 = *(const float4*)(bSrc + (size_t)kt * 32 + 4);
    }
  };
  auto WRITEB = [&](int buf) {
    if (hasB) {
      uint4 w;
      w.x = cvt2bf(rb0.x, rb0.y); w.y = cvt2bf(rb0.z, rb0.w);
      w.z = cvt2bf(rb1.x, rb1.y); w.w = cvt2bf(rb1.z, rb1.w);
      *(uint4*)(ldsB + buf * 6144 + bDst) = w;
    }
  };

  auto COMP = [&](int buf) {
    const char* aB = lds + buf * ABUF_L + kq * PLANE_L + (wm * 64 + l15) * 16;
    const char* bB = ldsB + buf * 6144 + (wn * 48 + l15) * 64 + kq * 16;
    bf16x8 af[4], bf[3];
    #pragma unroll
    for (int fm = 0; fm < 4; ++fm) af[fm] = *(const bf16x8*)(aB + fm * 256);
    #pragma unroll
    for (int fn = 0; fn < 3; ++fn) bf[fn] = *(const bf16x8*)(bB + fn * 1024);
    #pragma unroll
    for (int fm = 0; fm < 4; ++fm)
      #pragma unroll
      for (int fn = 0; fn < 3; ++fn)
        acc[fm][fn] = __builtin_amdgcn_mfma_f32_16x16x32_bf16(af[fm], bf[fn], acc[fm][fn], 0, 0, 0);
  };

  STAGEA(0, 0);
  LOADB(0);
  WRITEB(0);
  __syncthreads();
  for (int kt = 0; kt < NKT; ++kt) {
    int nb = (kt + 1) & 1;
    if (kt + 1 < NKT) { STAGEA(kt + 1, nb); LOADB(kt + 1); }
    COMP(kt & 1);
    if (kt + 1 < NKT) WRITEB(nb);
    __syncthreads();
  }

  #pragma unroll
  for (int fm = 0; fm < 4; ++fm) {
    #pragma unroll
    for (int j = 0; j < 4; ++j) {
      int rL = m0 + wm * 64 + fm * 16 + kq * 4 + j;
      int aidx = (rL < n_e) ? list[base + rL] : -1;
      #pragma unroll
      for (int fn = 0; fn < 3; ++fn) {
        int col = nt * BN2 + wn * 48 + fn * 16 + l15;
        if (aidx >= 0)
          out[(size_t)aidx * HIDDEN + col] = acc[fm][fn][j] + dbias[e * HIDDEN + col];
      }
    }
  }
}

extern "C" void kernel_launch(void* const* d_in, const int* in_sizes, int n_in,
                              void* d_out, int out_size, void* d_ws, size_t ws_size,
                              hipStream_t stream) {
  const float* t     = (const float*)d_in[0];
  const int*   eidx  = (const int*)d_in[1];
  const float* gup   = (const float*)d_in[2];
  const float* gub   = (const float*)d_in[3];
  const float* dwn   = (const float*)d_in[4];
  const float* dbias = (const float*)d_in[5];
  float* out = (float*)d_out;

  char* ws = (char*)d_ws;
  char* atile = ws;
  char* utile = ws + IMG_BYTES;
  int* meta = (int*)(ws + 2 * IMG_BYTES);
  int* list = meta + 32;

  route_count<<<1, 256, 0, stream>>>(eidx, meta);
  route_scatter<<<NPAIR / 256, 256, 0, stream>>>(eidx, meta, list);
  gather_a<<<NPAIR, 256, 0, stream>>>(t, eidx, meta, list, atile);

  dim3 g1(NEXP, GUP_ROWS / BN1, 2);   // 8 x 45 x 2 (mt=1 = safety tier, normally exits)
  gemm1_swiglu<<<g1, 640, 0, stream>>>(atile, gup, gub, meta, utile);

  dim3 g2(NEXP, HIDDEN / BN2, 2);     // 8 x 30 x 2
  gemm2_down<<<g2, 640, 0, stream>>>(utile, dwn, dbias, meta, list, out);
}

// Round 10
// 334.538 us; speedup vs baseline: 2.5188x; 2.5188x over previous
//
#include <hip/hip_runtime.h>
#include <hip/hip_bf16.h>

#define HIDDEN   2880
#define INTER    2880
#define NEXP     8
#define GUP_ROWS 5760
#define NPAIR    2048

#define NKT   45             // k-tiles of 64
#define BM    320
#define BN    96             // both gemms
#define TILE_B  40960        // per (tile,kt): 8 planes x 320 rows x 16B
#define PLANE_B 5120

#define MAXTILES 15
#define IMG_BYTES ((size_t)MAXTILES * NKT * TILE_B)   // ~27.6 MB

#define ABUF 40960           // LDS A buffer (one kt)
#define BBUF 24576           // LDS B buffer (96 cols x 256B f32)

using bf16x8 = __attribute__((ext_vector_type(8))) short;
using f32x4  = __attribute__((ext_vector_type(4))) float;

typedef const __attribute__((address_space(1))) unsigned GBuf;
typedef __attribute__((address_space(3))) unsigned LBuf;

__device__ __forceinline__ void gl2lds(const void* g, void* l) {
  __builtin_amdgcn_global_load_lds((GBuf*)g, (LBuf*)l, 16, 0, 0);
}
__device__ __forceinline__ void wait_vm8() {
  asm volatile("s_waitcnt vmcnt(8)" ::: "memory");
  __builtin_amdgcn_sched_barrier(0);
}
__device__ __forceinline__ void wait_vm0() {
  asm volatile("s_waitcnt vmcnt(0)" ::: "memory");
  __builtin_amdgcn_sched_barrier(0);
}
__device__ __forceinline__ void barrier() {
  __builtin_amdgcn_sched_barrier(0);
  __builtin_amdgcn_s_barrier();
  __builtin_amdgcn_sched_barrier(0);
}

__device__ __forceinline__ unsigned cvt2bf(float a, float b) {
  union { __hip_bfloat16 h; unsigned short s; } x, y;
  x.h = __float2bfloat16(a);
  y.h = __float2bfloat16(b);
  return (unsigned)x.s | ((unsigned)y.s << 16);
}
__device__ __forceinline__ bf16x8 cvt8(const float4& lo, const float4& hi) {
  union { bf16x8 v; unsigned u[4]; } r;
  r.u[0] = cvt2bf(lo.x, lo.y);
  r.u[1] = cvt2bf(lo.z, lo.w);
  r.u[2] = cvt2bf(hi.x, hi.y);
  r.u[3] = cvt2bf(hi.z, hi.w);
  return r.v;
}

// ---------------- routing ----------------
// meta: [0..7]=counts [8..15]=row offsets [16..23]=cursor [24..31]=tile base
__global__ void route_count(const int* __restrict__ eidx, int* __restrict__ meta) {
  __shared__ int cnt[NEXP];
  int t = threadIdx.x;
  if (t < NEXP) cnt[t] = 0;
  __syncthreads();
  for (int a = t; a < NPAIR; a += 256) atomicAdd(&cnt[eidx[a]], 1);
  __syncthreads();
  if (t == 0) {
    int off = 0, toff = 0;
    for (int e = 0; e < NEXP; ++e) {
      meta[e] = cnt[e];
      meta[8 + e] = off;
      meta[16 + e] = off;
      meta[24 + e] = toff;
      off += cnt[e];
      toff += (cnt[e] + BM - 1) / BM;
    }
  }
}

__global__ void route_scatter(const int* __restrict__ eidx, int* __restrict__ meta,
                              int* __restrict__ list) {
  int a = blockIdx.x * 256 + threadIdx.x;
  int e = eidx[a];
  int pos = atomicAdd(&meta[16 + e], 1);
  list[pos] = a;
}

// ---------------- gather A rows -> bf16 tiled fragment image ----------------
// layout: [tile][kt(45)][plane p 0..7][row 0..319][16B],  k = kt*64 + p*8 + j
__global__ void gather_a(const float* __restrict__ t, const int* __restrict__ eidx,
                         const int* __restrict__ meta, const int* __restrict__ list,
                         char* __restrict__ atile) {
  const int i = blockIdx.x;
  const int a = list[i];
  const int e = eidx[a];
  const int r = i - meta[8 + e];
  const int tile = meta[24 + e] + r / BM;
  const int row = r % BM;
  const float* src = t + (size_t)(a >> 2) * HIDDEN;
  for (int ch = threadIdx.x; ch < HIDDEN / 8; ch += 256) {
    int kt = ch >> 3, p = ch & 7;
    const float4* s = (const float4*)(src + ch * 8);
    float4 v0 = s[0], v1 = s[1];
    uint4 w;
    w.x = cvt2bf(v0.x, v0.y); w.y = cvt2bf(v0.z, v0.w);
    w.z = cvt2bf(v1.x, v1.y); w.w = cvt2bf(v1.z, v1.w);
    *(uint4*)(atile + (size_t)(tile * NKT + kt) * TILE_B + p * PLANE_B + row * 16) = w;
  }
}

// ---------------- GEMM core: 8 waves (4 wm x 2 wn), tile 320x96, BK=64 ----------------
// LDS: A dbuf 2x40KB + B(f32) dbuf 2x24KB = 128KB -> 1 block/CU.
// Staging per iter per wave: 5 A-gl2lds + 3 B-gl2lds = 8  -> vmcnt(8) = 1-iter cover.
template<int NCOLS_TOT, bool SWIGLU>
__global__ __launch_bounds__(512, 2)
void gemm_core(const char* __restrict__ aimg,
               const float* __restrict__ wgt,
               const float* __restrict__ wbias,
               const int* __restrict__ meta,
               const int* __restrict__ list,
               char* __restrict__ uimg,
               float* __restrict__ out)
{
  const int e = blockIdx.x, nt = blockIdx.y, mt = blockIdx.z;
  const int n_e = meta[e];
  const int m0 = mt * BM;
  if (m0 >= n_e) return;
  const int tile = meta[24 + e] + mt;

  __shared__ __align__(16) char lds[2 * ABUF + 2 * BBUF];   // 128 KB
  char* ldsB = lds + 2 * ABUF;

  const int tid = threadIdx.x, lane = tid & 63, wid = tid >> 6;
  const int wm = wid >> 1, wn = wid & 1;
  const int kq = lane >> 4, l15 = lane & 15;

  const char* aSrcBase = aimg + (size_t)tile * NKT * TILE_B;
  // A: 40 chunks of 1KB (linear image copy), 5 per wave
  const char* srcA[5];
  int dstA[5];
  #pragma unroll
  for (int j = 0; j < 5; ++j) {
    int c = wid * 5 + j;
    srcA[j] = aSrcBase + c * 1024 + lane * 16;
    dstA[j] = c * 1024;
  }
  // B: 24 chunks of 1KB (4 cols x 256B), 3 per wave; bank-swizzle in SOURCE addr
  const char* srcB[3];
  int dstB[3];
  #pragma unroll
  for (int j = 0; j < 3; ++j) {
    int cb = wid * 3 + j;
    int col = nt * BN + cb * 4 + (lane >> 4);
    int s16 = lane & 15;
    int swz = (((s16 >> 1) ^ (col & 7)) << 5) | ((s16 & 1) << 4);
    srcB[j] = (const char*)wgt + ((size_t)(e * NCOLS_TOT + col) * HIDDEN) * 4 + swz;
    dstB[j] = cb * 1024;
  }

  auto STAGE = [&](int kt, int buf) {
    #pragma unroll
    for (int j = 0; j < 5; ++j)
      gl2lds(srcA[j] + (size_t)kt * TILE_B, lds + buf * ABUF + dstA[j]);
    #pragma unroll
    for (int j = 0; j < 3; ++j)
      gl2lds(srcB[j] + (size_t)kt * 256, ldsB + buf * BBUF + dstB[j]);
  };

  f32x4 acc[5][3];
  #pragma unroll
  for (int fm = 0; fm < 5; ++fm)
    #pragma unroll
    for (int fn = 0; fn < 3; ++fn)
      acc[fm][fn] = f32x4{0.f, 0.f, 0.f, 0.f};

  auto COMP = [&](int buf) {
    const char* aT = lds + buf * ABUF;
    const char* bT = ldsB + buf * BBUF;
    #pragma unroll
    for (int s = 0; s < 2; ++s) {
      const char* aB = aT + (s * 4 + kq) * PLANE_B + (wm * 80 + l15) * 16;
      bf16x8 af[5], bf[3];
      #pragma unroll
      for (int fm = 0; fm < 5; ++fm) af[fm] = *(const bf16x8*)(aB + fm * 256);
      #pragma unroll
      for (int fn = 0; fn < 3; ++fn) {
        int col = wn * 48 + fn * 16 + l15;
        int slot = ((s * 4 + kq) ^ (col & 7)) << 5;
        const char* cp = bT + col * 256 + slot;
        float4 lo = *(const float4*)cp;
        float4 hi = *(const float4*)(cp + 16);
        bf[fn] = cvt8(lo, hi);
      }
      #pragma unroll
      for (int fm = 0; fm < 5; ++fm)
        #pragma unroll
        for (int fn = 0; fn < 3; ++fn)
          acc[fm][fn] = __builtin_amdgcn_mfma_f32_16x16x32_bf16(af[fm], bf[fn], acc[fm][fn], 0, 0, 0);
    }
  };

  STAGE(0, 0);
  for (int kt = 0; kt < NKT; ++kt) {
    if (kt + 1 < NKT) { STAGE(kt + 1, (kt + 1) & 1); wait_vm8(); }
    else wait_vm0();
    barrier();
    COMP(kt & 1);
    barrier();
  }

  if (SWIGLU) {
    #pragma unroll
    for (int fm = 0; fm < 5; ++fm) {
      #pragma unroll
      for (int fn = 0; fn < 3; ++fn) {
        const int colg = nt * BN + wn * 48 + fn * 16 + l15;
        const float bias = wbias[e * NCOLS_TOT + colg];
        #pragma unroll
        for (int j = 0; j < 4; ++j) {
          float h = acc[fm][fn][j] + bias;
          float other = __shfl_xor(h, 1, 64);
          int rowin = wm * 80 + fm * 16 + kq * 4 + j;
          if (!(lane & 1) && (m0 + rowin) < n_e) {
            float xg = fminf(h, 7.0f);
            float xl = fminf(fmaxf(other, -7.0f), 7.0f);
            float og = xg / (1.0f + __expf(-1.702f * xg));
            float uv = og * (xl + 1.0f);
            int uc = colg >> 1;                      // 0..2879
            int kt2 = uc >> 6, p2 = (uc >> 3) & 7;
            *(__hip_bfloat16*)(uimg + (size_t)(tile * NKT + kt2) * TILE_B +
                p2 * PLANE_B + rowin * 16 + (uc & 7) * 2) = __float2bfloat16(uv);
          }
        }
      }
    }
  } else {
    const int base = meta[8 + e];
    #pragma unroll
    for (int fm = 0; fm < 5; ++fm) {
      #pragma unroll
      for (int j = 0; j < 4; ++j) {
        int rL = m0 + wm * 80 + fm * 16 + kq * 4 + j;
        int aidx = (rL < n_e) ? list[base + rL] : -1;
        #pragma unroll
        for (int fn = 0; fn < 3; ++fn) {
          int col = nt * BN + wn * 48 + fn * 16 + l15;
          if (aidx >= 0)
            out[(size_t)aidx * HIDDEN + col] = acc[fm][fn][j] + wbias[e * NCOLS_TOT + col];
        }
      }
    }
  }
}

extern "C" void kernel_launch(void* const* d_in, const int* in_sizes, int n_in,
                              void* d_out, int out_size, void* d_ws, size_t ws_size,
                              hipStream_t stream) {
  const float* t     = (const float*)d_in[0];
  const int*   eidx  = (const int*)d_in[1];
  const float* gup   = (const float*)d_in[2];
  const float* gub   = (const float*)d_in[3];
  const float* dwn   = (const float*)d_in[4];
  const float* dbias = (const float*)d_in[5];
  float* out = (float*)d_out;

  char* ws = (char*)d_ws;
  char* atile = ws;
  char* utile = ws + IMG_BYTES;
  int* meta = (int*)(ws + 2 * IMG_BYTES);
  int* list = meta + 32;

  route_count<<<1, 256, 0, stream>>>(eidx, meta);
  route_scatter<<<NPAIR / 256, 256, 0, stream>>>(eidx, meta, list);
  gather_a<<<NPAIR, 256, 0, stream>>>(t, eidx, meta, list, atile);

  dim3 g1(NEXP, GUP_ROWS / BN, 2);   // 8 x 60 x 2 (mt=1 safety tier, normally exits)
  gemm_core<GUP_ROWS, true><<<g1, 512, 0, stream>>>(atile, gup, gub, meta, list, utile, out);

  dim3 g2(NEXP, HIDDEN / BN, 2);     // 8 x 30 x 2
  gemm_core<HIDDEN, false><<<g2, 512, 0, stream>>>(utile, dwn, dbias, meta, list, nullptr, out);
}